// Round 4
// baseline (1439.841 us; speedup 1.0000x reference)
//
#include <hip/hip_runtime.h>
#include <math.h>

#define H 128
#define SLOTS 8

typedef float f32x4 __attribute__((ext_vector_type(4)));
typedef __bf16 bf16x8 __attribute__((ext_vector_type(8)));

__device__ __forceinline__ float fast_tanh(float v) {
    // tanh(v) = 1 - 2/(exp(2v)+1); exact at +-inf saturation
    float e = __expf(2.0f * v);
    float r = __builtin_amdgcn_rcpf(e + 1.0f);
    return fmaf(-2.0f, r, 1.0f);
}

// batch may be int32 or int64 (sorted, values < 2^31): int64 detected via
// high-word-zero at int32 index n-1 (odd index = high word of elem (n-1)/2).
__device__ __forceinline__ int bload(const int* __restrict__ batch, bool is64,
                                     long long i) {
    return is64 ? batch[(size_t)i * 2] : batch[i];
}

// Fully fused attention pooling. s = tanh(x@w1+b1)@w2 (b2 cancels in softmax),
// unnormalized weights e=exp(s) (|s|<~6, fp32-safe), out[g]+=e*x, denom[g]+=e.
// x read ONCE; rows live in registers as bf16 hi+lo (exact to 2^-16).
//
// R3 lesson (counters): 8.6M global fp32 atomics cost a 64B RMW line EACH at
// TCC<->HBM (550MB write + 550MB fetch observed) -- atomics, not spills, were
// the bottleneck. R4: block-level LDS slot accumulation (slot = g - gfirst,
// sorted batch => ~2 graphs per 256-row tile), flush once per tile with
// coalesced zero-skip atomics; tile-interior graphs are exclusive -> plain
// stores. Global atomics drop ~10x.
__global__ __launch_bounds__(512, 2) void k_fused(
    const float* __restrict__ x, const int* __restrict__ batch,
    const float* __restrict__ w1, const float* __restrict__ b1,
    const float* __restrict__ w2, float* __restrict__ out,
    float* __restrict__ denom, int n, int ntiles)
{
    __shared__ __bf16 wsm[2 * H * H];     // [hi|lo][n][k swizzled] = 64 KB
    __shared__ float accS[SLOTS * H];     // per-graph pooled partials (4 KB)
    __shared__ float accD[SLOTS];         // per-graph denom partials

    const int tid = threadIdx.x;

    // ---- stage w1 (k-major [k][n]) -> LDS transposed [n][k], bf16 hi/lo ----
    for (int idx = tid; idx < H * H; idx += 512) {
        int k = idx >> 7, nn = idx & 127;      // w1[k][nn], coalesced in nn
        float v = w1[idx];
        __bf16 h = (__bf16)v;
        __bf16 l = (__bf16)(v - (float)h);
        int c = (k >> 3) ^ (nn & 15);          // 16B-chunk XOR swizzle
        int pos = nn * H + c * 8 + (k & 7);
        wsm[pos] = h;
        wsm[H * H + pos] = l;
    }

    const int wv = tid >> 6;       // wave 0..7
    const int lane = tid & 63;
    const int p = lane & 15;       // A: m-row / B: n-col / D: col
    const int q = lane >> 4;       // A,B: k-group / D: row-group

    const bool is64 = (batch[n - 1] == 0);

    __syncthreads();  // weights ready (read-only below)

    // tile = 256 rows per block (two 128-row passes; regs reused across passes)
    for (int tile = blockIdx.x; tile < ntiles; tile += (int)gridDim.x) {
        const long long tbase = (long long)tile * 256;

        // zero accumulator slots
        for (int i = tid; i < SLOTS * H; i += 512) accS[i] = 0.0f;
        if (tid < SLOTS) accD[tid] = 0.0f;
        const int gfirst = bload(batch, is64, tbase);  // broadcast load
        __syncthreads();

        for (int pass = 0; pass < 2; ++pass) {
            const long long base = tbase + pass * 128 + wv * 16;
            const long long r0 = base + p;
            const bool ok = (r0 < (long long)n);

            // ---- load 1 M-tile of x, split to bf16 hi/lo ----
            // lane (p,q) holds row base+p, cols kc*32 + q*8 + j
            bf16x8 ah[4], al[4];
            {
                const float4* rp = (const float4*)(x + r0 * H);
                #pragma unroll
                for (int kc = 0; kc < 4; ++kc) {
                    float4 u0 = {0.f, 0.f, 0.f, 0.f}, u1 = {0.f, 0.f, 0.f, 0.f};
                    if (ok) { u0 = rp[kc * 8 + q * 2]; u1 = rp[kc * 8 + q * 2 + 1]; }
                    float vals[8] = {u0.x, u0.y, u0.z, u0.w, u1.x, u1.y, u1.z, u1.w};
                    #pragma unroll
                    for (int j = 0; j < 8; ++j) {
                        __bf16 h = (__bf16)vals[j];
                        ah[kc][j] = h;
                        al[kc][j] = (__bf16)(vals[j] - (float)h);
                    }
                }
            }

            // ---- per-nt MFMA + immediate epilogue fold ----
            float part[4] = {0.f, 0.f, 0.f, 0.f};
            #pragma unroll
            for (int nt = 0; nt < 8; ++nt) {
                const int nn = nt * 16 + p;
                f32x4 acc = {0.f, 0.f, 0.f, 0.f};
                #pragma unroll
                for (int kc = 0; kc < 4; ++kc) {
                    const int c = (kc * 4 + q) ^ p;  // undo swizzle (nn&15 == p)
                    const __bf16* bb = &wsm[nn * H + c * 8];
                    bf16x8 bh = *(const bf16x8*)bb;
                    bf16x8 bl = *(const bf16x8*)(bb + H * H);
                    acc = __builtin_amdgcn_mfma_f32_16x16x32_bf16(ah[kc], bh, acc, 0, 0, 0);
                    acc = __builtin_amdgcn_mfma_f32_16x16x32_bf16(al[kc], bh, acc, 0, 0, 0);
                    acc = __builtin_amdgcn_mfma_f32_16x16x32_bf16(ah[kc], bl, acc, 0, 0, 0);
                }
                const float b1v = b1[nn];
                const float w2v = w2[nn];
                #pragma unroll
                for (int rg = 0; rg < 4; ++rg)
                    part[rg] = fmaf(fast_tanh(acc[rg] + b1v), w2v, part[rg]);
            }

            // ---- reduce over 16 col-lanes ----
            #pragma unroll
            for (int off = 1; off < 16; off <<= 1) {
                #pragma unroll
                for (int rg = 0; rg < 4; ++rg)
                    part[rg] += __shfl_xor(part[rg], off);
            }

            // ---- redistribute: lane (p,q) takes s for row base+p ----
            float e;
            {
                const int srcl = (p >> 2) * 16;
                float a0 = __shfl(part[0], srcl);
                float a1 = __shfl(part[1], srcl);
                float a2 = __shfl(part[2], srcl);
                float a3 = __shfl(part[3], srcl);
                int rs = p & 3;
                float sv = (rs == 0) ? a0 : (rs == 1) ? a1 : (rs == 2) ? a2 : a3;
                e = ok ? __expf(sv) : 0.0f;
            }

            int ga = ok ? bload(batch, is64, r0) : 0x7FFFFFFF;

            // ---- segmented accumulate into LDS slots (sorted: 1-2 iters) ----
            while (true) {
                int gm = ga;
                #pragma unroll
                for (int off = 1; off < 16; off <<= 1)
                    gm = min(gm, __shfl_xor(gm, off));
                if (gm == 0x7FFFFFFF) break;

                float ea = (ga == gm) ? e : 0.0f;
                float dsum = ea;
                #pragma unroll
                for (int off = 1; off < 16; off <<= 1)
                    dsum += __shfl_xor(dsum, off);

                const int slot = gm - gfirst;  // wave-uniform, >= 0 (sorted)

                #pragma unroll
                for (int kc = 0; kc < 4; ++kc) {
                    float t[8];
                    #pragma unroll
                    for (int j = 0; j < 8; ++j)
                        t[j] = ea * ((float)ah[kc][j] + (float)al[kc][j]);
                    #pragma unroll
                    for (int off = 1; off < 16; off <<= 1) {
                        #pragma unroll
                        for (int j = 0; j < 8; ++j)
                            t[j] += __shfl_xor(t[j], off);
                    }
                    if (p == 0) {
                        if (slot < SLOTS) {
                            float* ob = &accS[slot * H + kc * 32 + q * 8];
                            #pragma unroll
                            for (int j = 0; j < 8; ++j) atomicAdd(&ob[j], t[j]);
                        } else {  // >8 graph boundaries in tile: rare fallback
                            float* ob = out + (size_t)gm * H + kc * 32 + q * 8;
                            #pragma unroll
                            for (int j = 0; j < 8; ++j) atomicAdd(&ob[j], t[j]);
                        }
                    }
                }
                if (lane == 0) {
                    if (slot < SLOTS) atomicAdd(&accD[slot], dsum);
                    else atomicAdd(&denom[gm], dsum);
                }

                if (ga == gm) ga = 0x7FFFFFFF;
            }
        }

        __syncthreads();  // all waves' LDS accumulation done

        // ---- flush slots: coalesced, zero-skip; interior graphs exclusive ----
        {
            const long long lastr =
                (tbase + 255 < (long long)n) ? tbase + 255 : (long long)n - 1;
            const int glast = bload(batch, is64, lastr);
            for (int i = tid; i < SLOTS * H; i += 512) {
                const int slot = i >> 7, c = i & 127;
                const int g = gfirst + slot;
                const float v = accS[i];
                if (v != 0.0f) {  // atomicAdd(p,0) is identity -> safe to skip
                    if (g > gfirst && g < glast)         // all rows inside tile
                        out[(size_t)g * H + c] = v;      // exclusive: plain store
                    else
                        atomicAdd(&out[(size_t)g * H + c], v);
                }
            }
            if (tid < SLOTS) {
                const int g = gfirst + tid;
                const float d = accD[tid];
                if (d != 0.0f) {
                    if (g > gfirst && g < glast) denom[g] = d;
                    else atomicAdd(&denom[g], d);
                }
            }
        }
        __syncthreads();  // flush reads done before next tile zeroes accS
    }
}

// zero the atomic accumulators (out + denom) -- must run every iteration
__global__ void k_zero(float* __restrict__ out, float* __restrict__ denom,
                       int nf, int g_count)
{
    int i = blockIdx.x * blockDim.x + threadIdx.x;
    if (i < nf) out[i] = 0.0f;
    else if (i < nf + g_count) denom[i - nf] = 0.0f;
}

// out[g,:] /= denom[g]  (denom>0 guard matches reference; empty graphs stay 0)
__global__ void k_norm(float* __restrict__ out, const float* __restrict__ denom,
                       int total4)
{
    int i = blockIdx.x * blockDim.x + threadIdx.x;
    if (i >= total4) return;
    int g = i >> 5;  // 32 float4 per H=128 row
    float d = denom[g];
    float inv = (d > 0.0f) ? (1.0f / d) : 1.0f;
    float4 v = ((float4*)out)[i];
    v.x *= inv; v.y *= inv; v.z *= inv; v.w *= inv;
    ((float4*)out)[i] = v;
}

extern "C" void kernel_launch(void* const* d_in, const int* in_sizes, int n_in,
                              void* d_out, int out_size, void* d_ws, size_t ws_size,
                              hipStream_t stream)
{
    const float* x     = (const float*)d_in[0];
    const int*   batch = (const int*)d_in[1];
    const float* w1    = (const float*)d_in[2];
    const float* b1    = (const float*)d_in[3];
    const float* w2    = (const float*)d_in[4];
    // b2 unused: constant bias cancels exactly in softmax weights
    const int n = in_sizes[0] / H;       // 1e6 rows
    const int G = out_size / H;          // 4096 graphs
    float* out = (float*)d_out;

    float* denom = (float*)d_ws;         // G floats

    const int nf = G * H;
    const int tiles = (n + 255) / 256;   // 256 rows per block tile
    k_zero<<<(nf + G + 255) / 256, 256, 0, stream>>>(out, denom, nf, G);
    k_fused<<<1024, 512, 0, stream>>>(x, batch, w1, b1, w2, out, denom, n, tiles);
    k_norm<<<(G * 32 + 255) / 256, 256, 0, stream>>>(out, denom, G * 32);
}